// Round 15
// baseline (146.732 us; speedup 1.0000x reference)
//
#include <hip/hip_runtime.h>

#define N_NODES 100000
#define N_EDGES 1600000
#define HID 32
#define BN_EPS 1e-5f

#define BSZ   128                    // nodes per bucket
#define NBUCK 782                    // 782*128 = 100096 >= 100000
#define CAP   3072                   // edge capacity per bucket (avg 2047)
#define NSL   250                    // edge slices (250*6400 = 1,600,000 exactly)
#define EPSL  6400                   // edges per slice, int4-aligned
#define E4PB  1600                   // int4 loads per block
#define SRC_MASK 0x1FFFFu
#define GSTRIDE 16                   // gcur padding: one 64B line per bucket

// ============================ main path ============================

// One pass over edges: int4 loads -> LDS hist(782) -> line-padded global
// bump-alloc -> wave-shuffle scan -> LDS bucket-sort stage -> burst copy-out.
__global__ __launch_bounds__(1024)
void bin_kernel(const int* __restrict__ src, const int* __restrict__ dst,
                int* __restrict__ gcur, unsigned* __restrict__ ebuf) {
    __shared__ unsigned stageP[EPSL];          // 25,600 B
    __shared__ unsigned short stageB[EPSL];    // 12,800 B
    __shared__ int hist[NBUCK], curs[NBUCK], delta[NBUCK];
    __shared__ int wsum[16];
    int tid = threadIdx.x, blk = blockIdx.x;
    const int4* d4 = (const int4*)dst + blk * E4PB;
    const int4* s4 = (const int4*)src + blk * E4PB;

    int4 dv0, dv1, sv0, sv1;
    bool v2 = (tid + 1024) < E4PB;
    dv0 = d4[tid]; sv0 = s4[tid];
    if (v2) { dv1 = d4[tid + 1024]; sv1 = s4[tid + 1024]; }

    for (int j = tid; j < NBUCK; j += 1024) hist[j] = 0;
    __syncthreads();

    unsigned pk[8]; int bk[8];
    {
        int dd[8] = {dv0.x, dv0.y, dv0.z, dv0.w, dv1.x, dv1.y, dv1.z, dv1.w};
        int ss[8] = {sv0.x, sv0.y, sv0.z, sv0.w, sv1.x, sv1.y, sv1.z, sv1.w};
#pragma unroll
        for (int i = 0; i < 8; ++i) {
            if (i < 4 || v2) {
                bk[i] = dd[i] >> 7;
                pk[i] = ((unsigned)(dd[i] & 127) << 17) | (unsigned)ss[i];
                atomicAdd(&hist[bk[i]], 1);
            } else bk[i] = -1;
        }
    }
    __syncthreads();

    // two-level wave-shuffle inclusive scan over 1024 (3 barriers)
    int lane = tid & 63, wv = tid >> 6;
    int h = (tid < NBUCK) ? hist[tid] : 0;
    int v = h;
#pragma unroll
    for (int off = 1; off < 64; off <<= 1) {
        int u = __shfl_up(v, off);
        if (lane >= off) v += u;
    }
    if (lane == 63) wsum[wv] = v;
    __syncthreads();
    if (wv == 0) {
        int w = (lane < 16) ? wsum[lane] : 0;
#pragma unroll
        for (int off = 1; off < 16; off <<= 1) {
            int u = __shfl_up(w, off);
            if (lane >= off) w += u;
        }
        if (lane < 16) wsum[lane] = w;
    }
    __syncthreads();
    int incl = v + (wv ? wsum[wv - 1] : 0);
    if (tid < NBUCK) {
        int loff = incl - h;                       // block-local exclusive
        curs[tid] = loff;
        int gb = atomicAdd(&gcur[tid * GSTRIDE], h);   // line-padded bump-alloc
        delta[tid] = tid * CAP + gb - loff;
    }
    __syncthreads();
#pragma unroll
    for (int i = 0; i < 8; ++i)
        if (bk[i] >= 0) {
            int pos = atomicAdd(&curs[bk[i]], 1);
            stageP[pos] = pk[i];
            stageB[pos] = (unsigned short)bk[i];
        }
    __syncthreads();
    for (int j = tid; j < EPSL; j += 1024) {
        int b = stageB[j];
        ebuf[j + delta[b]] = stageP[j];
    }
}

// per bucket: uint4 edge reads, 8-way wave-replicated LDS degree hist, write xd
__global__ void degxd_kernel(const unsigned* __restrict__ ebuf, const int* __restrict__ gcur,
                             const float* __restrict__ x, float4* __restrict__ xd) {
    __shared__ int h8[8][BSZ];
    int tid = threadIdx.x, b = blockIdx.x, wv = tid >> 6;
    for (int j = tid; j < 8 * BSZ; j += 512) ((int*)h8)[j] = 0;
    __syncthreads();
    int cnt = gcur[b * GSTRIDE];
    const uint4* e4 = (const uint4*)(ebuf + (size_t)b * CAP);
    int nt4 = (cnt + 3) >> 2;
    for (int i = tid; i < nt4; i += 512) {
        uint4 q = e4[i];
        int rem = cnt - (i << 2);
        atomicAdd(&h8[wv][q.x >> 17], 1);
        if (rem > 1) atomicAdd(&h8[wv][q.y >> 17], 1);
        if (rem > 2) atomicAdd(&h8[wv][q.z >> 17], 1);
        if (rem > 3) atomicAdd(&h8[wv][q.w >> 17], 1);
    }
    __syncthreads();
    if (tid < BSZ) {
        int n = (b << 7) + tid;
        if (n < N_NODES) {
            int deg = 0;
#pragma unroll
            for (int k = 0; k < 8; ++k) deg += h8[k][tid];
            float rd = rsqrtf(1.0f + (float)deg);
            xd[n] = make_float4(x[3 * n] * rd, x[3 * n + 1] * rd, x[3 * n + 2] * rd, rd);
        }
    }
}

// per bucket: uint4 edge reads, 4 independent xd gathers/iter, 8-way replicated
// LDS S accumulate, plain S4 store, fused 9-scalar BN stats
__global__ void accum_kernel(const unsigned* __restrict__ ebuf, const int* __restrict__ gcur,
                             const float4* __restrict__ xd, float4* __restrict__ S4,
                             float* __restrict__ stats) {
    __shared__ float S[8][BSZ][3];     // 12 KB
    __shared__ float ls[8][9];
    int tid = threadIdx.x, b = blockIdx.x, wv = tid >> 6;
    for (int j = tid; j < 8 * BSZ * 3; j += 512) ((float*)S)[j] = 0.f;
    __syncthreads();
    int cnt = gcur[b * GSTRIDE];
    const uint4* e4 = (const uint4*)(ebuf + (size_t)b * CAP);
    int nt4 = (cnt + 3) >> 2;
    for (int i = tid; i < nt4; i += 512) {
        uint4 q = e4[i];
        int rem = cnt - (i << 2);
        float4 v0 = xd[q.x & SRC_MASK];
        float4 v1, v2c, v3;
        if (rem > 1) v1 = xd[q.y & SRC_MASK];
        if (rem > 2) v2c = xd[q.z & SRC_MASK];
        if (rem > 3) v3 = xd[q.w & SRC_MASK];
        int l0 = (int)(q.x >> 17);
        atomicAdd(&S[wv][l0][0], v0.x);
        atomicAdd(&S[wv][l0][1], v0.y);
        atomicAdd(&S[wv][l0][2], v0.z);
        if (rem > 1) {
            int l = (int)(q.y >> 17);
            atomicAdd(&S[wv][l][0], v1.x);
            atomicAdd(&S[wv][l][1], v1.y);
            atomicAdd(&S[wv][l][2], v1.z);
        }
        if (rem > 2) {
            int l = (int)(q.z >> 17);
            atomicAdd(&S[wv][l][0], v2c.x);
            atomicAdd(&S[wv][l][1], v2c.y);
            atomicAdd(&S[wv][l][2], v2c.z);
        }
        if (rem > 3) {
            int l = (int)(q.w >> 17);
            atomicAdd(&S[wv][l][0], v3.x);
            atomicAdd(&S[wv][l][1], v3.y);
            atomicAdd(&S[wv][l][2], v3.z);
        }
    }
    __syncthreads();
    float st[9];
#pragma unroll
    for (int q2 = 0; q2 < 9; ++q2) st[q2] = 0.f;
    if (tid < BSZ) {
        int n = (b << 7) + tid;
        if (n < N_NODES) {
            float4 self = xd[n];
            float sx = self.x, sy = self.y, sz = self.z;
#pragma unroll
            for (int k = 0; k < 8; ++k) {
                sx += S[k][tid][0]; sy += S[k][tid][1]; sz += S[k][tid][2];
            }
            S4[n] = make_float4(sx, sy, sz, self.w);
            float ax = self.w * sx, ay = self.w * sy, az = self.w * sz;
            st[0] = ax; st[1] = ay; st[2] = az;
            st[3] = ax * ax; st[4] = ax * ay; st[5] = ax * az;
            st[6] = ay * ay; st[7] = ay * az; st[8] = az * az;
        }
    }
    for (int m = 1; m < 64; m <<= 1)
#pragma unroll
        for (int q2 = 0; q2 < 9; ++q2) st[q2] += __shfl_xor(st[q2], m);
    if ((tid & 63) == 0)
#pragma unroll
        for (int q2 = 0; q2 < 9; ++q2) ls[wv][q2] = st[q2];
    __syncthreads();
    if (tid < 9) {
        float s = 0.f;
#pragma unroll
        for (int w = 0; w < 8; ++w) s += ls[w][tid];
        atomicAdd(&stats[tid], s);
    }
}

// fused BN-fold + PReLU streaming output
__global__ void final_out_kernel(const float4* __restrict__ S4, const float* __restrict__ stats,
                                 const float* __restrict__ W, const float* __restrict__ bb,
                                 const float* __restrict__ gamma, const float* __restrict__ beta,
                                 const float* __restrict__ prelu, float* __restrict__ out) {
    __shared__ float cb[4 * HID];
    int tid = threadIdx.x;
    if (tid < HID) {
        int c = tid;
        float m1x = stats[0], m1y = stats[1], m1z = stats[2];
        float Mxx = stats[3], Mxy = stats[4], Mxz = stats[5];
        float Myy = stats[6], Myz = stats[7], Mzz = stats[8];
        float w0 = W[c], w1 = W[HID + c], w2 = W[2 * HID + c];
        const float invn = 1.0f / (float)N_NODES;
        float m1w = m1x * w0 + m1y * w1 + m1z * w2;
        float mean = m1w * invn + bb[c];
        float quad = w0 * w0 * Mxx + w1 * w1 * Myy + w2 * w2 * Mzz
                   + 2.f * (w0 * w1 * Mxy + w0 * w2 * Mxz + w1 * w2 * Myz);
        float ex2 = quad * invn + 2.f * bb[c] * m1w * invn + bb[c] * bb[c];
        float var = ex2 - mean * mean;
        float sc = gamma[c] * rsqrtf(var + BN_EPS);
        cb[c] = w0 * sc;
        cb[HID + c] = w1 * sc;
        cb[2 * HID + c] = w2 * sc;
        cb[3 * HID + c] = bb[c] * sc + (beta[c] - mean * sc);
    }
    __syncthreads();
    float a = prelu[0];
    int stride = gridDim.x * blockDim.x;
    for (int t = blockIdx.x * blockDim.x + tid; t < N_NODES * HID; t += stride) {
        int n = t >> 5, c = t & 31;
        float4 s = S4[n];
        float y = s.w * (s.x * cb[c] + s.y * cb[HID + c] + s.z * cb[2 * HID + c])
                + cb[3 * HID + c];
        out[t] = y >= 0.f ? y : a * y;
    }
}

// ============================ fallback (round-4) path ============================

__global__ void fb_count_kernel(const int* __restrict__ dst, int* __restrict__ cnt) {
    int e = blockIdx.x * blockDim.x + threadIdx.x;
    if (e < N_EDGES) atomicAdd(&cnt[dst[e]], 1);
}

__global__ void fb_xd_kernel(const float* __restrict__ x, const int* __restrict__ cnt,
                             float4* __restrict__ xd, float4* __restrict__ S4) {
    int n = blockIdx.x * blockDim.x + threadIdx.x;
    if (n >= N_NODES) return;
    float rd = rsqrtf(1.0f + (float)cnt[n]);
    float4 v = make_float4(x[3 * n] * rd, x[3 * n + 1] * rd, x[3 * n + 2] * rd, rd);
    xd[n] = v;
    S4[n] = v;
}

__global__ void fb_scatter_kernel(const int* __restrict__ src, const int* __restrict__ dst,
                                  const float4* __restrict__ xd, float4* __restrict__ S4) {
    int e = blockIdx.x * blockDim.x + threadIdx.x;
    if (e >= N_EDGES) return;
    int s = src[e], d = dst[e];
    float4 v = xd[s];
    float* p = (float*)&S4[d];
    atomicAdd(p + 0, v.x);
    atomicAdd(p + 1, v.y);
    atomicAdd(p + 2, v.z);
}

__global__ void fb_stats_kernel(const float4* __restrict__ S4, float* __restrict__ stats) {
    __shared__ float ls[4][9];
    int tid = threadIdx.x;
    int n = blockIdx.x * blockDim.x + tid;
    float st[9];
#pragma unroll
    for (int q = 0; q < 9; ++q) st[q] = 0.f;
    if (n < N_NODES) {
        float4 s = S4[n];
        float ax = s.w * s.x, ay = s.w * s.y, az = s.w * s.z;
        st[0] = ax; st[1] = ay; st[2] = az;
        st[3] = ax * ax; st[4] = ax * ay; st[5] = ax * az;
        st[6] = ay * ay; st[7] = ay * az; st[8] = az * az;
    }
    for (int m = 1; m < 64; m <<= 1)
#pragma unroll
        for (int q = 0; q < 9; ++q) st[q] += __shfl_xor(st[q], m);
    int wv = tid >> 6;
    if ((tid & 63) == 0)
#pragma unroll
        for (int q = 0; q < 9; ++q) ls[wv][q] = st[q];
    __syncthreads();
    if (tid < 9) {
        float s = ls[0][tid] + ls[1][tid] + ls[2][tid] + ls[3][tid];
        atomicAdd(&stats[tid], s);
    }
}

// ============================ launch ============================

extern "C" void kernel_launch(void* const* d_in, const int* in_sizes, int n_in,
                              void* d_out, int out_size, void* d_ws, size_t ws_size,
                              hipStream_t stream) {
    const float* x     = (const float*)d_in[0];
    const int*   ei    = (const int*)d_in[1];   // [2, E]: src row then dst row
    const float* W     = (const float*)d_in[2];
    const float* b     = (const float*)d_in[3];
    const float* gamma = (const float*)d_in[4];
    const float* beta  = (const float*)d_in[5];
    const float* prelu = (const float*)d_in[6];

    const int* src = ei;
    const int* dst = ei + N_EDGES;
    char* ws = (char*)d_ws;
    float* out = (float*)d_out;

    // ---- ws layout (main path), total 12,859,456 B ----
    // gcur  @ 0          int[782*16] line-padded  (50,048) -> pad 50,176
    // stats @ 50,176     float[16]                (64)     -> memset covers [0,50,240)
    // ebuf  @ 50,240     u32[NBUCK*CAP]           (9,609,216) -> 9,659,456 (16B-aligned)
    // xd    @ 9,659,456  float4[100000]           (1,600,000) -> 11,259,456
    // S4    @ 11,259,456 float4[100000]           (1,600,000) -> 12,859,456
    const size_t NEEDED = 12859456;

    if (ws_size >= NEEDED) {
        int*      gcur  = (int*)(ws);
        float*    stats = (float*)(ws + 50176);
        unsigned* ebuf  = (unsigned*)(ws + 50240);
        float4*   xd    = (float4*)(ws + 9659456);
        float4*   S4    = (float4*)(ws + 11259456);

        hipMemsetAsync(ws, 0, 50240, stream);
        bin_kernel<<<NSL, 1024, 0, stream>>>(src, dst, gcur, ebuf);
        degxd_kernel<<<NBUCK, 512, 0, stream>>>(ebuf, gcur, x, xd);
        accum_kernel<<<NBUCK, 512, 0, stream>>>(ebuf, gcur, xd, S4, stats);
        final_out_kernel<<<2048, 256, 0, stream>>>(S4, stats, W, b, gamma, beta, prelu, out);
    } else {
        // fallback: round-4 direct-atomic path (ws need ~3.6 MB)
        int*    cnt   = (int*)(ws);
        float*  stats = (float*)(ws + 400000);
        float4* xd    = (float4*)(ws + 400640);
        float4* S4    = (float4*)(ws + 2000640);

        hipMemsetAsync(ws, 0, 400064, stream);
        fb_count_kernel<<<(N_EDGES + 255) / 256, 256, 0, stream>>>(dst, cnt);
        fb_xd_kernel<<<(N_NODES + 255) / 256, 256, 0, stream>>>(x, cnt, xd, S4);
        fb_scatter_kernel<<<(N_EDGES + 255) / 256, 256, 0, stream>>>(src, dst, xd, S4);
        fb_stats_kernel<<<(N_NODES + 255) / 256, 256, 0, stream>>>(S4, stats);
        final_out_kernel<<<2048, 256, 0, stream>>>(S4, stats, W, b, gamma, beta, prelu, out);
    }
}